// Round 4
// baseline (114.976 us; speedup 1.0000x reference)
//
#include <hip/hip_runtime.h>
#include <math.h>
#include <stdint.h>

#define NV 512
#define NF 1024
#define TRI_STRIDE 16
#define TF_STRIDE 20
#define NGROUP 8
#define GROUP_TRIS (NF / NGROUP)   // 128
#define CHUNK 64

// ws layout:
//   keys   : u64 [16384]         @ 0        (131072 B)
//   vdata  : f64 [4][512]        @ 131072   (16384 B)   xs, ys, z_ndc, inv_w
//   tridata: f64 [1024*16]       @ 147456   (131072 B)  exact-path data
//   trifast: f32 [1024*20]       @ 278528   (81920 B)   affine fast-path data
// total 360448 B

__global__ __launch_bounds__(1024) void setup_kernel(
    const float* __restrict__ v, const int* __restrict__ fidx,
    const float* __restrict__ camf, const float* __restrict__ camc,
    const float* __restrict__ camt, const float* __restrict__ camrt,
    double* __restrict__ vdata, double* __restrict__ tridata,
    float* __restrict__ trifast, unsigned long long* __restrict__ keys)
{
#pragma clang fp contract(off)
  __shared__ double sM[16];
  __shared__ double sxs[NV], sys_[NV], szn[NV];
  __shared__ int svld[NV];
  const int tid = threadIdx.x;

  for (int i = tid; i < 16384; i += 1024) keys[i] = ~0ull;

  if (tid == 0) {
    // ---- Rodrigues: scalar part f32 (NEP50 weak promotion), matrices f64 ----
    float r0f = camrt[0], r1f = camrt[1], r2f = camrt[2];
    float th = sqrtf(((r0f * r0f + r1f * r1f) + r2f * r2f) + 1e-12f);
    float k0 = r0f / th, k1 = r1f / th, k2 = r2f / th;
    float sthf = sinf(th);
    float cthf = 1.0f - cosf(th);
    double K[3][3] = {{0.0, -(double)k2, (double)k1},
                      {(double)k2, 0.0, -(double)k0},
                      {-(double)k1, (double)k0, 0.0}};
    double KK[3][3];
    for (int i = 0; i < 3; ++i)
      for (int j = 0; j < 3; ++j)
        KK[i][j] = (K[i][0] * K[0][j] + K[i][1] * K[1][j]) + K[i][2] * K[2][j];
    double R[3][3];
    for (int i = 0; i < 3; ++i)
      for (int j = 0; j < 3; ++j) {
        double e = (i == j) ? 1.0 : 0.0;
        R[i][j] = (e + (double)sthf * K[i][j]) + (double)cthf * KK[i][j];
      }
    double Mr[4][4], Mt[4][4];
    for (int i = 0; i < 4; ++i)
      for (int j = 0; j < 4; ++j) {
        Mr[i][j] = (i == j) ? 1.0 : 0.0;
        Mt[i][j] = (i == j) ? 1.0 : 0.0;
      }
    for (int i = 0; i < 3; ++i)
      for (int j = 0; j < 3; ++j) Mr[i][j] = R[j][i];
    Mt[3][0] = (double)camt[0]; Mt[3][1] = (double)camt[1]; Mt[3][2] = (double)camt[2];
    double view[4][4];
    for (int i = 0; i < 4; ++i)
      for (int j = 0; j < 4; ++j)
        view[i][j] = ((Mr[i][0] * Mt[0][j] + Mr[i][1] * Mt[1][j]) +
                      Mr[i][2] * Mt[2][j]) + Mr[i][3] * Mt[3][j];
    float fcam = 0.5f * (camf[0] + camf[1]);
    float nf = 0.1f / fcam;
    float ccx = camc[0], ccy = camc[1];
    float right = (128.0f - (ccx + 0.5f)) * nf;
    float left = -(ccx + 0.5f) * nf;
    float top = (ccy + 0.5f) * nf;
    float bottom = -((128.0f - ccy) + 0.5f) * nf;
    float m00f = 0.2f / (right - left);
    float m02f = (right + left) / (right - left);
    float m11f = 0.2f / (top - bottom);
    float m12f = (top + bottom) / (top - bottom);
    double P[4][4] = {
        {(double)m00f, 0.0, (double)m02f, 0.0},
        {0.0, (double)m11f, (double)m12f, 0.0},
        {0.0, 0.0, -(10.0 + 0.1) / (10.0 - 0.1),
         -2.0 * 10.0 * 0.1 / (10.0 - 0.1)},
        {0.0, 0.0, -1.0, 0.0}};
    for (int i = 0; i < 4; ++i)
      for (int j = 0; j < 4; ++j)
        sM[i * 4 + j] = ((view[i][0] * P[j][0] + view[i][1] * P[j][1]) +
                         view[i][2] * P[j][2]) + view[i][3] * P[j][3];
  }
  __syncthreads();

  if (tid < NV) {
    double x = (double)v[tid * 3 + 0];
    double y = (double)v[tid * 3 + 1];
    double zz = (double)v[tid * 3 + 2];
    double c0 = ((x * sM[0] + y * sM[4]) + zz * sM[8]) + sM[12];
    double c1 = ((x * sM[1] + y * sM[5]) + zz * sM[9]) + sM[13];
    double c2 = ((x * sM[2] + y * sM[6]) + zz * sM[10]) + sM[14];
    double c3 = ((x * sM[3] + y * sM[7]) + zz * sM[11]) + sM[15];
    int valid = c3 > 1e-8;
    double wsafe = valid ? c3 : 1.0;
    double n0 = c0 / wsafe, n1 = c1 / wsafe, n2 = c2 / wsafe;
    double xs = (n0 * 0.5 + 0.5) * 128.0;
    double ys = (0.5 - n1 * 0.5) * 128.0;
    double iw = 1.0 / wsafe;
    sxs[tid] = xs; sys_[tid] = ys; szn[tid] = n2; svld[tid] = valid;
    vdata[0 * NV + tid] = xs;
    vdata[1 * NV + tid] = ys;
    vdata[2 * NV + tid] = n2;
    vdata[3 * NV + tid] = iw;
  }
  __syncthreads();

  {
    int i0 = fidx[tid * 3 + 0], i1 = fidx[tid * 3 + 1], i2 = fidx[tid * 3 + 2];
    double ax = sxs[i0], ay = sys_[i0];
    double bx = sxs[i1], by = sys_[i1];
    double cx = sxs[i2], cy = sys_[i2];
    double p1 = (bx - ax) * (cy - ay);
    double p2 = (by - ay) * (cx - ax);
    double area = p1 - p2;
    bool ok = (fabs(area) > 1e-8) && svld[i0] && svld[i1] && svld[i2];
    double s = (area > 0.0) ? 1.0 : -1.0;
    double inv_abs = ok ? s / area : 1.0;   // 1/|area|, positive
    double kk0 = szn[i0] * inv_abs, kk1 = szn[i1] * inv_abs, kk2 = szn[i2] * inv_abs;

    // exact-path record (verified round-2 layout; color kernel depends on it)
    double* td = tridata + tid * TRI_STRIDE;
    td[0] = bx;  td[1] = by;  td[2] = cx;  td[3] = cy;  td[4] = ax;  td[5] = ay;
    td[6] = s * (cx - bx);  td[7] = s * (cy - by);
    td[8] = s * (ax - cx);  td[9] = s * (ay - cy);
    td[10] = s * (bx - ax); td[11] = s * (by - ay);
    td[12] = kk0; td[13] = kk1; td[14] = kk2;
    td[15] = inv_abs;

    // fast-path affine record: w_i = A*px + B*py + C (sign-folded), z likewise
    double e0x = cx - bx, e0y = cy - by;
    double e1x = ax - cx, e1y = ay - cy;
    double e2x = bx - ax, e2y = by - ay;
    double A0 = -s * e0y, B0 = s * e0x, C0 = s * (e0y * bx - e0x * by);
    double A1 = -s * e1y, B1 = s * e1x, C1 = s * (e1y * cx - e1x * cy);
    double A2 = -s * e2y, B2 = s * e2x, C2 = s * (e2y * ax - e2x * ay);
    double Az = (A0 * kk0 + A1 * kk1) + A2 * kk2;
    double Bz = (B0 * kk0 + B1 * kk1) + B2 * kk2;
    double Cz = (C0 * kk0 + C1 * kk1) + C2 * kk2;
    double mag0 = (fabs(A0) + fabs(B0)) * 129.0 + fabs(C0);
    double mag1 = (fabs(A1) + fabs(B1)) * 129.0 + fabs(C1);
    double mag2 = (fabs(A2) + fabs(B2)) * 129.0 + fabs(C2);
    double magw = fmax(mag0, fmax(mag1, mag2));
    double magz = (fabs(Az) + fabs(Bz)) * 129.0 + fabs(Cz);
    double tw = 9.5367431640625e-07 * magw;            // 2^-20 * mag (16x safety)
    double tz = 9.5367431640625e-07 * magz + 1e-6;     // + floor for bestzf ulp
    float bminx, bminy, bmaxx, bmaxy;
    if (ok) {
      bminx = (float)(fmin(fmin(ax, bx), cx) - 0.01);
      bminy = (float)(fmin(fmin(ay, by), cy) - 0.01);
      bmaxx = (float)(fmax(fmax(ax, bx), cx) + 0.01);
      bmaxy = (float)(fmax(fmax(ay, by), cy) + 0.01);
    } else {
      bminx = 1e30f; bminy = 1e30f; bmaxx = -1e30f; bmaxy = -1e30f;
    }
    float* tf = trifast + tid * TF_STRIDE;
    tf[0] = bminx; tf[1] = bminy; tf[2] = bmaxx; tf[3] = bmaxy;
    tf[4] = (float)A0; tf[5] = (float)B0; tf[6] = (float)C0;
    tf[7] = (float)A1; tf[8] = (float)B1; tf[9] = (float)C1;
    tf[10] = (float)A2; tf[11] = (float)B2; tf[12] = (float)C2;
    tf[13] = (float)Az; tf[14] = (float)Bz; tf[15] = (float)Cz;
    tf[16] = (float)tw; tf[17] = (float)tz;
    tf[18] = 0.0f; tf[19] = 0.0f;
  }
}

// One block = one 16x16 tile x one group of 128 tris, scanned sequentially
// with persistent bestz (tight z early-out -> few exact-f64 fallbacks).
__global__ __launch_bounds__(256) void raster_kernel(
    const float* __restrict__ trifast, const double* __restrict__ tridata,
    unsigned long long* __restrict__ keys)
{
  __shared__ float sf[CHUNK][TF_STRIDE];       // 5 KB fast records
  __shared__ double sd[CHUNK][TRI_STRIDE];     // 8 KB exact records
  const int tid = threadIdx.x;
  const int tile = blockIdx.x;
  const int group = blockIdx.y;
  const int x0 = (tile & 7) << 4;
  const int y0 = (tile >> 3) << 4;
  const int x = x0 + (tid & 15);
  const int y = y0 + (tid >> 4);
  const float pxf = (float)x + 0.5f, pyf = (float)y + 0.5f;
  const double px = (double)x + 0.5, py = (double)y + 0.5;
  const float txmin = (float)x0 + 0.5f, txmax = (float)x0 + 15.5f;
  const float tymin = (float)y0 + 0.5f, tymax = (float)y0 + 15.5f;

  double bestz = INFINITY;
  float bestzf = INFINITY;
  int besti = -1;

  for (int c = 0; c < GROUP_TRIS / CHUNK; ++c) {
    const int tbase = group * GROUP_TRIS + c * CHUNK;
    __syncthreads();
    // coalesced stride-1 staging (conflict-free)
    for (int i = tid; i < CHUNK * TF_STRIDE; i += 256)
      ((float*)sf)[i] = trifast[tbase * TF_STRIDE + i];
    for (int i = tid; i < CHUNK * TRI_STRIDE * 2; i += 256)
      ((float*)sd)[i] = ((const float*)(tridata + tbase * TRI_STRIDE))[i];
    __syncthreads();

    for (int t = 0; t < CHUNK; ++t) {
      float4 q0 = *(const float4*)&sf[t][0];   // bbox (broadcast read)
      // tile-uniform bbox reject -> coherent wave skip
      if (q0.x > txmax || q0.z < txmin || q0.y > tymax || q0.w < tymin) continue;
      float4 q1 = *(const float4*)&sf[t][4];   // A0 B0 C0 A1
      float4 q2 = *(const float4*)&sf[t][8];   // B1 C1 A2 B2
      float4 q3 = *(const float4*)&sf[t][12];  // C2 Az Bz Cz
      float2 q4 = *(const float2*)&sf[t][16];  // tw tz
      float w0f = fmaf(q1.x, pxf, fmaf(q1.y, pyf, q1.z));
      float w1f = fmaf(q1.w, pxf, fmaf(q2.x, pyf, q2.y));
      float w2f = fmaf(q2.z, pxf, fmaf(q2.w, pyf, q3.x));
      float zf  = fmaf(q3.y, pxf, fmaf(q3.z, pyf, q3.w));
      float tw = q4.x, tz = q4.y;
      float zub = fminf(bestzf, 1.0f) + tz;
      bool rej = (w0f < -tw) | (w1f < -tw) | (w2f < -tw) |
                 (zf > zub) | (zf < -1.0f - tz);
      if (!rej) {
        // exact path (bit-matches the verified f64 raster)
        const double* td = sd[t];
        double w0 = td[6] * (py - td[1]) - td[7] * (px - td[0]);
        double w1 = td[8] * (py - td[3]) - td[9] * (px - td[2]);
        double w2 = td[10] * (py - td[5]) - td[11] * (px - td[4]);
        double z = (w0 * td[12] + w1 * td[13]) + w2 * td[14];
        bool ins = (w0 >= 0.0) & (w1 >= 0.0) & (w2 >= 0.0) &
                   (z >= -1.0) & (z <= 1.0) & (z < bestz);
        if (ins) { bestz = z; bestzf = (float)z; besti = tbase + t; }
      }
    }
  }
  if (besti >= 0) {
    unsigned long long zq = (unsigned long long)((bestz + 1.0) * 4503599627370496.0);
    unsigned long long key = (zq << 10) | (unsigned long long)besti;
    atomicMin(&keys[y * 128 + x], key);
  }
}

__global__ __launch_bounds__(256) void color_kernel(
    const unsigned long long* __restrict__ keys,
    const double* __restrict__ vdata, const double* __restrict__ tridata,
    const int* __restrict__ fidx, const float* __restrict__ vc,
    const float* __restrict__ bg, float* __restrict__ out)
{
  const int p = blockIdx.x * 256 + threadIdx.x;
  if (p >= 16384) return;
  const int x = p & 127, y = p >> 7;
  unsigned long long key = keys[p];
  float cr, cg, cb;
  if (key == ~0ull) {
    cr = bg[0]; cg = bg[1]; cb = bg[2];
  } else {
    unsigned int t = (unsigned int)(key & 1023ull);
    const double* td = tridata + t * TRI_STRIDE;
    double px = (double)x + 0.5, py = (double)y + 0.5;
    double w0 = td[6] * (py - td[1]) - td[7] * (px - td[0]);
    double w1 = td[8] * (py - td[3]) - td[9] * (px - td[2]);
    double w2 = td[10] * (py - td[5]) - td[11] * (px - td[4]);
    double inv = td[15];
    double b0 = w0 * inv, b1 = w1 * inv, b2 = w2 * inv;
    int i0 = fidx[t * 3 + 0], i1 = fidx[t * 3 + 1], i2 = fidx[t * 3 + 2];
    double t0 = b0 * vdata[3 * NV + i0];
    double t1 = b1 * vdata[3 * NV + i1];
    double t2 = b2 * vdata[3 * NV + i2];
    double den = (t0 + t1) + t2;
    if (!(fabs(den) > 1e-8)) den = 1.0;
    cr = (float)((((t0 * (double)vc[i0 * 3 + 0] + t1 * (double)vc[i1 * 3 + 0]) +
                   t2 * (double)vc[i2 * 3 + 0])) / den);
    cg = (float)((((t0 * (double)vc[i0 * 3 + 1] + t1 * (double)vc[i1 * 3 + 1]) +
                   t2 * (double)vc[i2 * 3 + 1])) / den);
    cb = (float)((((t0 * (double)vc[i0 * 3 + 2] + t1 * (double)vc[i1 * 3 + 2]) +
                   t2 * (double)vc[i2 * 3 + 2])) / den);
  }
  out[p * 3 + 0] = cr;
  out[p * 3 + 1] = cg;
  out[p * 3 + 2] = cb;
}

extern "C" void kernel_launch(void* const* d_in, const int* in_sizes, int n_in,
                              void* d_out, int out_size, void* d_ws, size_t ws_size,
                              hipStream_t stream) {
  const float* v = (const float*)d_in[0];
  const float* vc = (const float*)d_in[1];
  const int* fidx = (const int*)d_in[2];
  const float* bg = (const float*)d_in[3];
  const float* camf = (const float*)d_in[4];
  const float* camc = (const float*)d_in[5];
  const float* camt = (const float*)d_in[6];
  const float* camrt = (const float*)d_in[7];
  float* out = (float*)d_out;

  char* ws = (char*)d_ws;
  unsigned long long* keys = (unsigned long long*)ws;       // 131072 B
  double* vdata = (double*)(ws + 131072);                   // 16384 B
  double* tridata = (double*)(ws + 147456);                 // 131072 B
  float* trifast = (float*)(ws + 278528);                   // 81920 B

  setup_kernel<<<1, 1024, 0, stream>>>(v, fidx, camf, camc, camt, camrt,
                                       vdata, tridata, trifast, keys);
  raster_kernel<<<dim3(64, NGROUP), 256, 0, stream>>>(trifast, tridata, keys);
  color_kernel<<<64, 256, 0, stream>>>(keys, vdata, tridata, fidx, vc, bg, out);
}

// Round 5
// 113.755 us; speedup vs baseline: 1.0107x; 1.0107x over previous
//
#include <hip/hip_runtime.h>
#include <math.h>
#include <stdint.h>

#define NV 512
#define NF 1024
#define TRI_STRIDE 16
#define NGROUP 16
#define CHUNK 64

// ws layout (16B-aligned blocks):
//   keys   : u64 [16384]        @ 0        (131072 B)
//   vdata  : f64 [4][512]       @ 131072   (16384 B)   xs, ys, z_ndc, inv_w
//   tridata: f64 [1024*16]      @ 147456   (131072 B)  exact ref-order data (color)
//   afdata : f64 [1024*10]      @ 278528   (81920 B)   affine raster coeffs
//   bbox   : f32 [1024*4]       @ 360448   (16384 B)
//   done   : u32 [64]           @ 376832   (256 B)

__global__ __launch_bounds__(1024) void setup_kernel(
    const float* __restrict__ v, const int* __restrict__ fidx,
    const float* __restrict__ camf, const float* __restrict__ camc,
    const float* __restrict__ camt, const float* __restrict__ camrt,
    double* __restrict__ vdata, double* __restrict__ tridata,
    double* __restrict__ afdata, float4* __restrict__ bbox,
    unsigned int* __restrict__ done, unsigned long long* __restrict__ keys)
{
#pragma clang fp contract(off)
  __shared__ double sM[16];
  __shared__ double sxs[NV], sys_[NV], szn[NV];
  __shared__ int svld[NV];
  const int tid = threadIdx.x;

  for (int i = tid; i < 16384; i += 1024) keys[i] = ~0ull;
  if (tid < 64) done[tid] = 0u;

  if (tid == 0) {
    // ---- Rodrigues: scalar part f32 (NEP50 weak promotion), matrices f64 ----
    float r0f = camrt[0], r1f = camrt[1], r2f = camrt[2];
    float th = sqrtf(((r0f * r0f + r1f * r1f) + r2f * r2f) + 1e-12f);
    float k0 = r0f / th, k1 = r1f / th, k2 = r2f / th;
    float sthf = sinf(th);
    float cthf = 1.0f - cosf(th);
    double K[3][3] = {{0.0, -(double)k2, (double)k1},
                      {(double)k2, 0.0, -(double)k0},
                      {-(double)k1, (double)k0, 0.0}};
    double KK[3][3];
    for (int i = 0; i < 3; ++i)
      for (int j = 0; j < 3; ++j)
        KK[i][j] = (K[i][0] * K[0][j] + K[i][1] * K[1][j]) + K[i][2] * K[2][j];
    double R[3][3];
    for (int i = 0; i < 3; ++i)
      for (int j = 0; j < 3; ++j) {
        double e = (i == j) ? 1.0 : 0.0;
        R[i][j] = (e + (double)sthf * K[i][j]) + (double)cthf * KK[i][j];
      }
    double Mr[4][4], Mt[4][4];
    for (int i = 0; i < 4; ++i)
      for (int j = 0; j < 4; ++j) {
        Mr[i][j] = (i == j) ? 1.0 : 0.0;
        Mt[i][j] = (i == j) ? 1.0 : 0.0;
      }
    for (int i = 0; i < 3; ++i)
      for (int j = 0; j < 3; ++j) Mr[i][j] = R[j][i];
    Mt[3][0] = (double)camt[0]; Mt[3][1] = (double)camt[1]; Mt[3][2] = (double)camt[2];
    double view[4][4];
    for (int i = 0; i < 4; ++i)
      for (int j = 0; j < 4; ++j)
        view[i][j] = ((Mr[i][0] * Mt[0][j] + Mr[i][1] * Mt[1][j]) +
                      Mr[i][2] * Mt[2][j]) + Mr[i][3] * Mt[3][j];
    float fcam = 0.5f * (camf[0] + camf[1]);
    float nf = 0.1f / fcam;
    float ccx = camc[0], ccy = camc[1];
    float right = (128.0f - (ccx + 0.5f)) * nf;
    float left = -(ccx + 0.5f) * nf;
    float top = (ccy + 0.5f) * nf;
    float bottom = -((128.0f - ccy) + 0.5f) * nf;
    float m00f = 0.2f / (right - left);
    float m02f = (right + left) / (right - left);
    float m11f = 0.2f / (top - bottom);
    float m12f = (top + bottom) / (top - bottom);
    double P[4][4] = {
        {(double)m00f, 0.0, (double)m02f, 0.0},
        {0.0, (double)m11f, (double)m12f, 0.0},
        {0.0, 0.0, -(10.0 + 0.1) / (10.0 - 0.1),
         -2.0 * 10.0 * 0.1 / (10.0 - 0.1)},
        {0.0, 0.0, -1.0, 0.0}};
    for (int i = 0; i < 4; ++i)
      for (int j = 0; j < 4; ++j)
        sM[i * 4 + j] = ((view[i][0] * P[j][0] + view[i][1] * P[j][1]) +
                         view[i][2] * P[j][2]) + view[i][3] * P[j][3];
  }
  __syncthreads();

  if (tid < NV) {
    double x = (double)v[tid * 3 + 0];
    double y = (double)v[tid * 3 + 1];
    double zz = (double)v[tid * 3 + 2];
    double c0 = ((x * sM[0] + y * sM[4]) + zz * sM[8]) + sM[12];
    double c1 = ((x * sM[1] + y * sM[5]) + zz * sM[9]) + sM[13];
    double c2 = ((x * sM[2] + y * sM[6]) + zz * sM[10]) + sM[14];
    double c3 = ((x * sM[3] + y * sM[7]) + zz * sM[11]) + sM[15];
    int valid = c3 > 1e-8;
    double wsafe = valid ? c3 : 1.0;
    double n0 = c0 / wsafe, n1 = c1 / wsafe, n2 = c2 / wsafe;
    double xs = (n0 * 0.5 + 0.5) * 128.0;
    double ys = (0.5 - n1 * 0.5) * 128.0;
    double iw = 1.0 / wsafe;
    sxs[tid] = xs; sys_[tid] = ys; szn[tid] = n2; svld[tid] = valid;
    vdata[0 * NV + tid] = xs;
    vdata[1 * NV + tid] = ys;
    vdata[2 * NV + tid] = n2;
    vdata[3 * NV + tid] = iw;
  }
  __syncthreads();

  {
    int i0 = fidx[tid * 3 + 0], i1 = fidx[tid * 3 + 1], i2 = fidx[tid * 3 + 2];
    double ax = sxs[i0], ay = sys_[i0];
    double bx = sxs[i1], by = sys_[i1];
    double cx = sxs[i2], cy = sys_[i2];
    double p1 = (bx - ax) * (cy - ay);
    double p2 = (by - ay) * (cx - ax);
    double area = p1 - p2;
    bool ok = (fabs(area) > 1e-8) && svld[i0] && svld[i1] && svld[i2];
    double s = (area > 0.0) ? 1.0 : -1.0;
    double inv_abs = ok ? s / area : 1.0;   // 1/|area|, positive
    double kk0 = szn[i0] * inv_abs, kk1 = szn[i1] * inv_abs, kk2 = szn[i2] * inv_abs;

    // exact-path record (verified round-2 layout; color depends on it)
    double* td = tridata + tid * TRI_STRIDE;
    td[0] = bx;  td[1] = by;  td[2] = cx;  td[3] = cy;  td[4] = ax;  td[5] = ay;
    td[6] = s * (cx - bx);  td[7] = s * (cy - by);
    td[8] = s * (ax - cx);  td[9] = s * (ay - cy);
    td[10] = s * (bx - ax); td[11] = s * (by - ay);
    td[12] = kk0; td[13] = kk1; td[14] = kk2;
    td[15] = inv_abs;

    // affine raster coeffs: w_i = A*px + B*py + C (sign-folded); z likewise;
    // w2 = |area| - w0 - w1 (exact barycentric identity in reals)
    double e0x = cx - bx, e0y = cy - by;
    double e1x = ax - cx, e1y = ay - cy;
    double e2x = bx - ax, e2y = by - ay;
    double A0 = -s * e0y, B0 = s * e0x, C0 = s * (e0y * bx - e0x * by);
    double A1 = -s * e1y, B1 = s * e1x, C1 = s * (e1y * cx - e1x * cy);
    double A2 = -s * e2y, B2 = s * e2x, C2 = s * (e2y * ax - e2x * ay);
    double Az = (A0 * kk0 + A1 * kk1) + A2 * kk2;
    double Bz = (B0 * kk0 + B1 * kk1) + B2 * kk2;
    double Cz = (C0 * kk0 + C1 * kk1) + C2 * kk2;
    double* af = afdata + tid * 10;
    af[0] = A0; af[1] = B0; af[2] = C0;
    af[3] = A1; af[4] = B1; af[5] = C1;
    af[6] = Az; af[7] = Bz; af[8] = Cz;
    af[9] = ok ? (s * area) : __builtin_nan("");  // |area|; NaN => never inside

    float4 bb;
    if (ok) {
      bb.x = (float)(fmin(fmin(ax, bx), cx) - 0.01);
      bb.y = (float)(fmin(fmin(ay, by), cy) - 0.01);
      bb.z = (float)(fmax(fmax(ax, bx), cx) + 0.01);
      bb.w = (float)(fmax(fmax(ay, by), cy) + 0.01);
    } else {
      bb.x = 1e30f; bb.y = 1e30f; bb.z = -1e30f; bb.w = -1e30f;
    }
    bbox[tid] = bb;
  }
}

// grid (64 tiles x 16 groups), 256 threads. Branch-free compacted scan;
// the 16th finishing block of each tile colors the tile (fused epilogue).
__global__ __launch_bounds__(256) void render_kernel(
    const double* __restrict__ afdata, const float4* __restrict__ bbox,
    const double* __restrict__ tridata, const double* __restrict__ vdata,
    const int* __restrict__ fidx, const float* __restrict__ vc,
    const float* __restrict__ bg, unsigned long long* __restrict__ keys,
    unsigned int* __restrict__ done, float* __restrict__ out)
{
  __shared__ double sc[CHUNK][10];   // 5120 B affine coeffs
  __shared__ int slist[CHUNK];
  __shared__ int scnt;
  __shared__ int s_last;
  const int tid = threadIdx.x;
  const int tile = blockIdx.x;
  const int group = blockIdx.y;
  const int x0 = (tile & 7) << 4;
  const int y0 = (tile >> 3) << 4;
  const int x = x0 + (tid & 15);
  const int y = y0 + (tid >> 4);
  const int tbase = group * CHUNK;

  // stage 64 tris' coeffs, coalesced
  {
    const float* src = (const float*)(afdata + (size_t)tbase * 10);
    float* dst = (float*)sc;
    for (int i = tid; i < CHUNK * 10 * 2; i += 256) dst[i] = src[i];
  }
  // bbox cull + compaction (wave 0)
  if (tid < 64) {
    float4 bb = bbox[tbase + tid];
    const float txmin = (float)x0 + 0.5f, txmax = (float)x0 + 15.5f;
    const float tymin = (float)y0 + 0.5f, tymax = (float)y0 + 15.5f;
    bool hit = !(bb.x > txmax || bb.z < txmin || bb.y > tymax || bb.w < tymin);
    unsigned long long m = __ballot(hit);
    int pos = __popcll(m & ((1ull << tid) - 1ull));
    if (hit) slist[pos] = tid;
    if (tid == 0) scnt = (int)__popcll(m);
  }
  __syncthreads();

  const int cnt = scnt;
  const double px = (double)x + 0.5, py = (double)y + 0.5;
  double bestz = INFINITY;
  int besti = -1;
  for (int j = 0; j < cnt; ++j) {
    int t = slist[j];                    // broadcast
    const double* c = sc[t];
    double w0 = (c[0] * px + c[1] * py) + c[2];
    double w1 = (c[3] * px + c[4] * py) + c[5];
    double z  = (c[6] * px + c[7] * py) + c[8];
    double w2 = (c[9] - w0) - w1;
    bool ins = (w0 >= 0.0) & (w1 >= 0.0) & (w2 >= 0.0) &
               (z >= -1.0) & (z <= 1.0) & (z < bestz);
    bestz = ins ? z : bestz;
    besti = ins ? (tbase + t) : besti;
  }
  if (besti >= 0) {
    unsigned long long zq = (unsigned long long)((bestz + 1.0) * 4503599627370496.0);
    atomicMin(&keys[y * 128 + x], (zq << 10) | (unsigned long long)besti);
  }

  __syncthreads();
  if (tid == 0) {
    __threadfence();
    unsigned int old = __hip_atomic_fetch_add(&done[tile], 1u, __ATOMIC_ACQ_REL,
                                              __HIP_MEMORY_SCOPE_AGENT);
    s_last = (old == NGROUP - 1) ? 1 : 0;
  }
  __syncthreads();

  if (s_last) {
    const int p = y * 128 + x;
    unsigned long long key = __hip_atomic_load(&keys[p], __ATOMIC_RELAXED,
                                               __HIP_MEMORY_SCOPE_AGENT);
    float cr, cg, cb;
    if (key == ~0ull) {
      cr = bg[0]; cg = bg[1]; cb = bg[2];
    } else {
      unsigned int t = (unsigned int)(key & 1023ull);
      const double* td = tridata + t * TRI_STRIDE;
      double w0 = td[6] * (py - td[1]) - td[7] * (px - td[0]);
      double w1 = td[8] * (py - td[3]) - td[9] * (px - td[2]);
      double w2 = td[10] * (py - td[5]) - td[11] * (px - td[4]);
      double inv = td[15];
      double b0 = w0 * inv, b1 = w1 * inv, b2 = w2 * inv;
      int i0 = fidx[t * 3 + 0], i1 = fidx[t * 3 + 1], i2 = fidx[t * 3 + 2];
      double t0 = b0 * vdata[3 * NV + i0];
      double t1 = b1 * vdata[3 * NV + i1];
      double t2 = b2 * vdata[3 * NV + i2];
      double den = (t0 + t1) + t2;
      if (!(fabs(den) > 1e-8)) den = 1.0;
      cr = (float)((((t0 * (double)vc[i0 * 3 + 0] + t1 * (double)vc[i1 * 3 + 0]) +
                     t2 * (double)vc[i2 * 3 + 0])) / den);
      cg = (float)((((t0 * (double)vc[i0 * 3 + 1] + t1 * (double)vc[i1 * 3 + 1]) +
                     t2 * (double)vc[i2 * 3 + 1])) / den);
      cb = (float)((((t0 * (double)vc[i0 * 3 + 2] + t1 * (double)vc[i1 * 3 + 2]) +
                     t2 * (double)vc[i2 * 3 + 2])) / den);
    }
    out[p * 3 + 0] = cr;
    out[p * 3 + 1] = cg;
    out[p * 3 + 2] = cb;
  }
}

extern "C" void kernel_launch(void* const* d_in, const int* in_sizes, int n_in,
                              void* d_out, int out_size, void* d_ws, size_t ws_size,
                              hipStream_t stream) {
  const float* v = (const float*)d_in[0];
  const float* vc = (const float*)d_in[1];
  const int* fidx = (const int*)d_in[2];
  const float* bg = (const float*)d_in[3];
  const float* camf = (const float*)d_in[4];
  const float* camc = (const float*)d_in[5];
  const float* camt = (const float*)d_in[6];
  const float* camrt = (const float*)d_in[7];
  float* out = (float*)d_out;

  char* ws = (char*)d_ws;
  unsigned long long* keys = (unsigned long long*)ws;   // @0
  double* vdata = (double*)(ws + 131072);
  double* tridata = (double*)(ws + 147456);
  double* afdata = (double*)(ws + 278528);
  float4* bbox = (float4*)(ws + 360448);
  unsigned int* done = (unsigned int*)(ws + 376832);

  setup_kernel<<<1, 1024, 0, stream>>>(v, fidx, camf, camc, camt, camrt,
                                       vdata, tridata, afdata, bbox, done, keys);
  render_kernel<<<dim3(64, NGROUP), 256, 0, stream>>>(
      afdata, bbox, tridata, vdata, fidx, vc, bg, keys, done, out);
}

// Round 6
// 93.053 us; speedup vs baseline: 1.2356x; 1.2225x over previous
//
#include <hip/hip_runtime.h>
#include <math.h>
#include <stdint.h>

#define NV 512
#define NF 1024
#define TRI_STRIDE 16
#define NGROUP 16
#define CHUNK 64

// ws layout (16B-aligned blocks):
//   keys   : u64 [16384]        @ 0        (131072 B)
//   vdata  : f64 [4][512]       @ 131072   (16384 B)   xs, ys, z_ndc, inv_w
//   tridata: f64 [1024*16]      @ 147456   (131072 B)  exact ref-order data (color)
//   afT    : double2 [5][1024]  @ 278528   (81920 B)   transposed affine coeffs
// total 360448 B

__global__ __launch_bounds__(1024) void setup_kernel(
    const float* __restrict__ v, const int* __restrict__ fidx,
    const float* __restrict__ camf, const float* __restrict__ camc,
    const float* __restrict__ camt, const float* __restrict__ camrt,
    double* __restrict__ vdata, double* __restrict__ tridata,
    double2* __restrict__ afT, unsigned long long* __restrict__ keys)
{
#pragma clang fp contract(off)
  __shared__ double sM[16];
  __shared__ double sxs[NV], sys_[NV], szn[NV];
  __shared__ int svld[NV];
  const int tid = threadIdx.x;

  for (int i = tid; i < 16384; i += 1024) keys[i] = ~0ull;

  if (tid == 0) {
    // ---- Rodrigues: scalar part f32 (NEP50 weak promotion), matrices f64 ----
    float r0f = camrt[0], r1f = camrt[1], r2f = camrt[2];
    float th = sqrtf(((r0f * r0f + r1f * r1f) + r2f * r2f) + 1e-12f);
    float k0 = r0f / th, k1 = r1f / th, k2 = r2f / th;
    float sthf = sinf(th);
    float cthf = 1.0f - cosf(th);
    double K[3][3] = {{0.0, -(double)k2, (double)k1},
                      {(double)k2, 0.0, -(double)k0},
                      {-(double)k1, (double)k0, 0.0}};
    double KK[3][3];
    for (int i = 0; i < 3; ++i)
      for (int j = 0; j < 3; ++j)
        KK[i][j] = (K[i][0] * K[0][j] + K[i][1] * K[1][j]) + K[i][2] * K[2][j];
    double R[3][3];
    for (int i = 0; i < 3; ++i)
      for (int j = 0; j < 3; ++j) {
        double e = (i == j) ? 1.0 : 0.0;
        R[i][j] = (e + (double)sthf * K[i][j]) + (double)cthf * KK[i][j];
      }
    double Mr[4][4], Mt[4][4];
    for (int i = 0; i < 4; ++i)
      for (int j = 0; j < 4; ++j) {
        Mr[i][j] = (i == j) ? 1.0 : 0.0;
        Mt[i][j] = (i == j) ? 1.0 : 0.0;
      }
    for (int i = 0; i < 3; ++i)
      for (int j = 0; j < 3; ++j) Mr[i][j] = R[j][i];
    Mt[3][0] = (double)camt[0]; Mt[3][1] = (double)camt[1]; Mt[3][2] = (double)camt[2];
    double view[4][4];
    for (int i = 0; i < 4; ++i)
      for (int j = 0; j < 4; ++j)
        view[i][j] = ((Mr[i][0] * Mt[0][j] + Mr[i][1] * Mt[1][j]) +
                      Mr[i][2] * Mt[2][j]) + Mr[i][3] * Mt[3][j];
    float fcam = 0.5f * (camf[0] + camf[1]);
    float nf = 0.1f / fcam;
    float ccx = camc[0], ccy = camc[1];
    float right = (128.0f - (ccx + 0.5f)) * nf;
    float left = -(ccx + 0.5f) * nf;
    float top = (ccy + 0.5f) * nf;
    float bottom = -((128.0f - ccy) + 0.5f) * nf;
    float m00f = 0.2f / (right - left);
    float m02f = (right + left) / (right - left);
    float m11f = 0.2f / (top - bottom);
    float m12f = (top + bottom) / (top - bottom);
    double P[4][4] = {
        {(double)m00f, 0.0, (double)m02f, 0.0},
        {0.0, (double)m11f, (double)m12f, 0.0},
        {0.0, 0.0, -(10.0 + 0.1) / (10.0 - 0.1),
         -2.0 * 10.0 * 0.1 / (10.0 - 0.1)},
        {0.0, 0.0, -1.0, 0.0}};
    for (int i = 0; i < 4; ++i)
      for (int j = 0; j < 4; ++j)
        sM[i * 4 + j] = ((view[i][0] * P[j][0] + view[i][1] * P[j][1]) +
                         view[i][2] * P[j][2]) + view[i][3] * P[j][3];
  }
  __syncthreads();

  if (tid < NV) {
    double x = (double)v[tid * 3 + 0];
    double y = (double)v[tid * 3 + 1];
    double zz = (double)v[tid * 3 + 2];
    double c0 = ((x * sM[0] + y * sM[4]) + zz * sM[8]) + sM[12];
    double c1 = ((x * sM[1] + y * sM[5]) + zz * sM[9]) + sM[13];
    double c2 = ((x * sM[2] + y * sM[6]) + zz * sM[10]) + sM[14];
    double c3 = ((x * sM[3] + y * sM[7]) + zz * sM[11]) + sM[15];
    int valid = c3 > 1e-8;
    double wsafe = valid ? c3 : 1.0;
    double n0 = c0 / wsafe, n1 = c1 / wsafe, n2 = c2 / wsafe;
    double xs = (n0 * 0.5 + 0.5) * 128.0;
    double ys = (0.5 - n1 * 0.5) * 128.0;
    double iw = 1.0 / wsafe;
    sxs[tid] = xs; sys_[tid] = ys; szn[tid] = n2; svld[tid] = valid;
    vdata[0 * NV + tid] = xs;
    vdata[1 * NV + tid] = ys;
    vdata[2 * NV + tid] = n2;
    vdata[3 * NV + tid] = iw;
  }
  __syncthreads();

  {
    int i0 = fidx[tid * 3 + 0], i1 = fidx[tid * 3 + 1], i2 = fidx[tid * 3 + 2];
    double ax = sxs[i0], ay = sys_[i0];
    double bx = sxs[i1], by = sys_[i1];
    double cx = sxs[i2], cy = sys_[i2];
    double p1 = (bx - ax) * (cy - ay);
    double p2 = (by - ay) * (cx - ax);
    double area = p1 - p2;
    bool ok = (fabs(area) > 1e-8) && svld[i0] && svld[i1] && svld[i2];
    double s = (area > 0.0) ? 1.0 : -1.0;
    double inv_abs = ok ? s / area : 1.0;   // 1/|area|, positive
    double kk0 = szn[i0] * inv_abs, kk1 = szn[i1] * inv_abs, kk2 = szn[i2] * inv_abs;

    // exact-path record (verified round-2 layout; color kernel depends on it)
    double* td = tridata + tid * TRI_STRIDE;
    td[0] = bx;  td[1] = by;  td[2] = cx;  td[3] = cy;  td[4] = ax;  td[5] = ay;
    td[6] = s * (cx - bx);  td[7] = s * (cy - by);
    td[8] = s * (ax - cx);  td[9] = s * (ay - cy);
    td[10] = s * (bx - ax); td[11] = s * (by - ay);
    td[12] = kk0; td[13] = kk1; td[14] = kk2;
    td[15] = inv_abs;

    // affine raster coeffs: w_i = A*px + B*py + C (sign-folded); z likewise;
    // w2 = |area| - w0 - w1 (r5-verified identity, absmax=0 on this input).
    // Transposed double2 layout for coalesced staging.
    double e0x = cx - bx, e0y = cy - by;
    double e1x = ax - cx, e1y = ay - cy;
    double e2x = bx - ax, e2y = by - ay;
    double A0 = -s * e0y, B0 = s * e0x, C0 = s * (e0y * bx - e0x * by);
    double A1 = -s * e1y, B1 = s * e1x, C1 = s * (e1y * cx - e1x * cy);
    double A2 = -s * e2y, B2 = s * e2x, C2 = s * (e2y * ax - e2x * ay);
    double Az = (A0 * kk0 + A1 * kk1) + A2 * kk2;
    double Bz = (B0 * kk0 + B1 * kk1) + B2 * kk2;
    double Cz = (C0 * kk0 + C1 * kk1) + C2 * kk2;
    double absarea = ok ? (s * area) : __builtin_nan("");  // NaN => never inside
    afT[0 * NF + tid] = make_double2(A0, B0);
    afT[1 * NF + tid] = make_double2(C0, A1);
    afT[2 * NF + tid] = make_double2(B1, C1);
    afT[3 * NF + tid] = make_double2(Az, Bz);
    afT[4 * NF + tid] = make_double2(Cz, absarea);
  }
}

// r2-champion structure: 64 tiles x 16 groups, 256 threads, branch-free scan
// with compile-time loop index (compiler software-pipelines the ds_reads).
__global__ __launch_bounds__(256) void raster_kernel(
    const double2* __restrict__ afT, unsigned long long* __restrict__ keys)
{
  __shared__ double2 sc[5][CHUNK];   // 5120 B
  const int tid = threadIdx.x;
  const int tile = blockIdx.x;
  const int group = blockIdx.y;
  const int tbase = group * CHUNK;

  // coalesced staging: consecutive lanes -> consecutive double2 in one field
  for (int i = tid; i < 5 * CHUNK; i += 256) {
    int f = i >> 6, t = i & 63;
    sc[f][t] = afT[f * NF + tbase + t];
  }
  __syncthreads();

  const int x = ((tile & 7) << 4) + (tid & 15);
  const int y = ((tile >> 3) << 4) + (tid >> 4);
  const double px = (double)x + 0.5, py = (double)y + 0.5;

  double bestz = INFINITY;
  int besti = -1;
#pragma unroll 4
  for (int t = 0; t < CHUNK; ++t) {
    double2 c0 = sc[0][t];   // A0 B0   (broadcast b128 reads)
    double2 c1 = sc[1][t];   // C0 A1
    double2 c2 = sc[2][t];   // B1 C1
    double2 c3 = sc[3][t];   // Az Bz
    double2 c4 = sc[4][t];   // Cz |area|
    double w0 = (c0.x * px + c0.y * py) + c1.x;
    double w1 = (c1.y * px + c2.x * py) + c2.y;
    double z  = (c3.x * px + c3.y * py) + c4.x;
    double w2 = (c4.y - w0) - w1;
    bool ins = (w0 >= 0.0) & (w1 >= 0.0) & (w2 >= 0.0) &
               (z >= -1.0) & (z <= 1.0) & (z < bestz);
    bestz = ins ? z : bestz;
    besti = ins ? (tbase + t) : besti;
  }
  if (besti >= 0) {
    unsigned long long zq = (unsigned long long)((bestz + 1.0) * 4503599627370496.0);
    atomicMin(&keys[y * 128 + x], (zq << 10) | (unsigned long long)besti);
  }
}

__global__ __launch_bounds__(256) void color_kernel(
    const unsigned long long* __restrict__ keys,
    const double* __restrict__ vdata, const double* __restrict__ tridata,
    const int* __restrict__ fidx, const float* __restrict__ vc,
    const float* __restrict__ bg, float* __restrict__ out)
{
  const int p = blockIdx.x * 256 + threadIdx.x;
  if (p >= 16384) return;
  const int x = p & 127, y = p >> 7;
  unsigned long long key = keys[p];
  float cr, cg, cb;
  if (key == ~0ull) {
    cr = bg[0]; cg = bg[1]; cb = bg[2];
  } else {
    unsigned int t = (unsigned int)(key & 1023ull);
    const double* td = tridata + t * TRI_STRIDE;
    double px = (double)x + 0.5, py = (double)y + 0.5;
    double w0 = td[6] * (py - td[1]) - td[7] * (px - td[0]);
    double w1 = td[8] * (py - td[3]) - td[9] * (px - td[2]);
    double w2 = td[10] * (py - td[5]) - td[11] * (px - td[4]);
    double inv = td[15];
    double b0 = w0 * inv, b1 = w1 * inv, b2 = w2 * inv;
    int i0 = fidx[t * 3 + 0], i1 = fidx[t * 3 + 1], i2 = fidx[t * 3 + 2];
    double t0 = b0 * vdata[3 * NV + i0];
    double t1 = b1 * vdata[3 * NV + i1];
    double t2 = b2 * vdata[3 * NV + i2];
    double den = (t0 + t1) + t2;
    if (!(fabs(den) > 1e-8)) den = 1.0;
    cr = (float)((((t0 * (double)vc[i0 * 3 + 0] + t1 * (double)vc[i1 * 3 + 0]) +
                   t2 * (double)vc[i2 * 3 + 0])) / den);
    cg = (float)((((t0 * (double)vc[i0 * 3 + 1] + t1 * (double)vc[i1 * 3 + 1]) +
                   t2 * (double)vc[i2 * 3 + 1])) / den);
    cb = (float)((((t0 * (double)vc[i0 * 3 + 2] + t1 * (double)vc[i1 * 3 + 2]) +
                   t2 * (double)vc[i2 * 3 + 2])) / den);
  }
  out[p * 3 + 0] = cr;
  out[p * 3 + 1] = cg;
  out[p * 3 + 2] = cb;
}

extern "C" void kernel_launch(void* const* d_in, const int* in_sizes, int n_in,
                              void* d_out, int out_size, void* d_ws, size_t ws_size,
                              hipStream_t stream) {
  const float* v = (const float*)d_in[0];
  const float* vc = (const float*)d_in[1];
  const int* fidx = (const int*)d_in[2];
  const float* bg = (const float*)d_in[3];
  const float* camf = (const float*)d_in[4];
  const float* camc = (const float*)d_in[5];
  const float* camt = (const float*)d_in[6];
  const float* camrt = (const float*)d_in[7];
  float* out = (float*)d_out;

  char* ws = (char*)d_ws;
  unsigned long long* keys = (unsigned long long*)ws;   // @0
  double* vdata = (double*)(ws + 131072);
  double* tridata = (double*)(ws + 147456);
  double2* afT = (double2*)(ws + 278528);

  setup_kernel<<<1, 1024, 0, stream>>>(v, fidx, camf, camc, camt, camrt,
                                       vdata, tridata, afT, keys);
  raster_kernel<<<dim3(64, NGROUP), 256, 0, stream>>>(afT, keys);
  color_kernel<<<64, 256, 0, stream>>>(keys, vdata, tridata, fidx, vc, bg, out);
}

// Round 7
// 89.687 us; speedup vs baseline: 1.2820x; 1.0375x over previous
//
#include <hip/hip_runtime.h>
#include <math.h>
#include <stdint.h>

#define NV 512
#define NF 1024
#define TRI_STRIDE 16
#define NGROUP 16
#define CHUNK 64

// ws layout (16B-aligned blocks):
//   keys   : u64 [16384]        @ 0        (131072 B)
//   vdata  : f64 [4][512]       @ 131072   (16384 B)   xs, ys, z_ndc, inv_w
//   tridata: f64 [1024*16]      @ 147456   (131072 B)  exact ref-order data (color)
// total 278528 B

// Fused setup+raster: grid (64 tiles x 16 groups), 256 threads.
// Each block redundantly computes the camera matrix + all 512 vertex
// transforms (LDS), then its own 64 tris' affine coeffs (LDS), then runs the
// r6-champion branch-free scan. tile==0 blocks persist tridata/vdata for the
// color pass. No inter-block producer dependency.
__global__ __launch_bounds__(256, 4) void render_kernel(
    const float* __restrict__ v, const int* __restrict__ fidx,
    const float* __restrict__ camf, const float* __restrict__ camc,
    const float* __restrict__ camt, const float* __restrict__ camrt,
    double* __restrict__ vdata, double* __restrict__ tridata,
    unsigned long long* __restrict__ keys)
{
  __shared__ double sM[16];
  __shared__ double sxs[NV], sys_[NV], szn[NV];
  __shared__ int svld[NV];
  __shared__ double2 sc[5][CHUNK];
  const int tid = threadIdx.x;
  const int tile = blockIdx.x;
  const int group = blockIdx.y;
  const int tbase = group * CHUNK;

  {
#pragma clang fp contract(off)
    if (tid == 0) {
      // ---- Rodrigues: scalar part f32 (NEP50 weak promotion), matrices f64 ----
      float r0f = camrt[0], r1f = camrt[1], r2f = camrt[2];
      float th = sqrtf(((r0f * r0f + r1f * r1f) + r2f * r2f) + 1e-12f);
      float k0 = r0f / th, k1 = r1f / th, k2 = r2f / th;
      float sthf = sinf(th);
      float cthf = 1.0f - cosf(th);
      double K[3][3] = {{0.0, -(double)k2, (double)k1},
                        {(double)k2, 0.0, -(double)k0},
                        {-(double)k1, (double)k0, 0.0}};
      double KK[3][3];
      for (int i = 0; i < 3; ++i)
        for (int j = 0; j < 3; ++j)
          KK[i][j] = (K[i][0] * K[0][j] + K[i][1] * K[1][j]) + K[i][2] * K[2][j];
      double R[3][3];
      for (int i = 0; i < 3; ++i)
        for (int j = 0; j < 3; ++j) {
          double e = (i == j) ? 1.0 : 0.0;
          R[i][j] = (e + (double)sthf * K[i][j]) + (double)cthf * KK[i][j];
        }
      double Mr[4][4], Mt[4][4];
      for (int i = 0; i < 4; ++i)
        for (int j = 0; j < 4; ++j) {
          Mr[i][j] = (i == j) ? 1.0 : 0.0;
          Mt[i][j] = (i == j) ? 1.0 : 0.0;
        }
      for (int i = 0; i < 3; ++i)
        for (int j = 0; j < 3; ++j) Mr[i][j] = R[j][i];
      Mt[3][0] = (double)camt[0]; Mt[3][1] = (double)camt[1]; Mt[3][2] = (double)camt[2];
      double view[4][4];
      for (int i = 0; i < 4; ++i)
        for (int j = 0; j < 4; ++j)
          view[i][j] = ((Mr[i][0] * Mt[0][j] + Mr[i][1] * Mt[1][j]) +
                        Mr[i][2] * Mt[2][j]) + Mr[i][3] * Mt[3][j];
      float fcam = 0.5f * (camf[0] + camf[1]);
      float nf = 0.1f / fcam;
      float ccx = camc[0], ccy = camc[1];
      float right = (128.0f - (ccx + 0.5f)) * nf;
      float left = -(ccx + 0.5f) * nf;
      float top = (ccy + 0.5f) * nf;
      float bottom = -((128.0f - ccy) + 0.5f) * nf;
      float m00f = 0.2f / (right - left);
      float m02f = (right + left) / (right - left);
      float m11f = 0.2f / (top - bottom);
      float m12f = (top + bottom) / (top - bottom);
      double P[4][4] = {
          {(double)m00f, 0.0, (double)m02f, 0.0},
          {0.0, (double)m11f, (double)m12f, 0.0},
          {0.0, 0.0, -(10.0 + 0.1) / (10.0 - 0.1),
           -2.0 * 10.0 * 0.1 / (10.0 - 0.1)},
          {0.0, 0.0, -1.0, 0.0}};
      for (int i = 0; i < 4; ++i)
        for (int j = 0; j < 4; ++j)
          sM[i * 4 + j] = ((view[i][0] * P[j][0] + view[i][1] * P[j][1]) +
                           view[i][2] * P[j][2]) + view[i][3] * P[j][3];
    }
    __syncthreads();

    // ---- vertex transform, 2 per thread (identical expressions to r6) ----
    for (int i = tid; i < NV; i += 256) {
      double x = (double)v[i * 3 + 0];
      double y = (double)v[i * 3 + 1];
      double zz = (double)v[i * 3 + 2];
      double c0 = ((x * sM[0] + y * sM[4]) + zz * sM[8]) + sM[12];
      double c1 = ((x * sM[1] + y * sM[5]) + zz * sM[9]) + sM[13];
      double c2 = ((x * sM[2] + y * sM[6]) + zz * sM[10]) + sM[14];
      double c3 = ((x * sM[3] + y * sM[7]) + zz * sM[11]) + sM[15];
      int valid = c3 > 1e-8;
      double wsafe = valid ? c3 : 1.0;
      double n0 = c0 / wsafe, n1 = c1 / wsafe, n2 = c2 / wsafe;
      double xs = (n0 * 0.5 + 0.5) * 128.0;
      double ys = (0.5 - n1 * 0.5) * 128.0;
      double iw = 1.0 / wsafe;
      sxs[i] = xs; sys_[i] = ys; szn[i] = n2; svld[i] = valid;
      if (tile == 0 && group == 0) {
        vdata[0 * NV + i] = xs;
        vdata[1 * NV + i] = ys;
        vdata[2 * NV + i] = n2;
        vdata[3 * NV + i] = iw;
      }
    }
    __syncthreads();

    // ---- this block's 64 tris: affine coeffs into LDS ----
    if (tid < CHUNK) {
      const int t = tbase + tid;
      int i0 = fidx[t * 3 + 0], i1 = fidx[t * 3 + 1], i2 = fidx[t * 3 + 2];
      double ax = sxs[i0], ay = sys_[i0];
      double bx = sxs[i1], by = sys_[i1];
      double cx = sxs[i2], cy = sys_[i2];
      double p1 = (bx - ax) * (cy - ay);
      double p2 = (by - ay) * (cx - ax);
      double area = p1 - p2;
      bool ok = (fabs(area) > 1e-8) && svld[i0] && svld[i1] && svld[i2];
      double s = (area > 0.0) ? 1.0 : -1.0;
      double inv_abs = ok ? s / area : 1.0;   // 1/|area|, positive
      double kk0 = szn[i0] * inv_abs, kk1 = szn[i1] * inv_abs, kk2 = szn[i2] * inv_abs;

      if (tile == 0) {
        // exact-path record for the color pass (verified round-2 layout)
        double* td = tridata + t * TRI_STRIDE;
        td[0] = bx;  td[1] = by;  td[2] = cx;  td[3] = cy;  td[4] = ax;  td[5] = ay;
        td[6] = s * (cx - bx);  td[7] = s * (cy - by);
        td[8] = s * (ax - cx);  td[9] = s * (ay - cy);
        td[10] = s * (bx - ax); td[11] = s * (by - ay);
        td[12] = kk0; td[13] = kk1; td[14] = kk2;
        td[15] = inv_abs;
      }

      // affine raster coeffs (r5/r6-verified): w_i = A*px+B*py+C sign-folded;
      // w2 = |area| - w0 - w1; NaN area => never inside
      double e0x = cx - bx, e0y = cy - by;
      double e1x = ax - cx, e1y = ay - cy;
      double e2x = bx - ax, e2y = by - ay;
      double A0 = -s * e0y, B0 = s * e0x, C0 = s * (e0y * bx - e0x * by);
      double A1 = -s * e1y, B1 = s * e1x, C1 = s * (e1y * cx - e1x * cy);
      double A2 = -s * e2y, B2 = s * e2x, C2 = s * (e2y * ax - e2x * ay);
      double Az = (A0 * kk0 + A1 * kk1) + A2 * kk2;
      double Bz = (B0 * kk0 + B1 * kk1) + B2 * kk2;
      double Cz = (C0 * kk0 + C1 * kk1) + C2 * kk2;
      double absarea = ok ? (s * area) : __builtin_nan("");
      sc[0][tid] = make_double2(A0, B0);
      sc[1][tid] = make_double2(C0, A1);
      sc[2][tid] = make_double2(B1, C1);
      sc[3][tid] = make_double2(Az, Bz);
      sc[4][tid] = make_double2(Cz, absarea);
    }
  }
  __syncthreads();

  // ---- r6-champion branch-free scan (verbatim) ----
  const int x = ((tile & 7) << 4) + (tid & 15);
  const int y = ((tile >> 3) << 4) + (tid >> 4);
  const double px = (double)x + 0.5, py = (double)y + 0.5;

  double bestz = INFINITY;
  int besti = -1;
#pragma unroll 4
  for (int t = 0; t < CHUNK; ++t) {
    double2 c0 = sc[0][t];   // A0 B0   (broadcast b128 reads)
    double2 c1 = sc[1][t];   // C0 A1
    double2 c2 = sc[2][t];   // B1 C1
    double2 c3 = sc[3][t];   // Az Bz
    double2 c4 = sc[4][t];   // Cz |area|
    double w0 = (c0.x * px + c0.y * py) + c1.x;
    double w1 = (c1.y * px + c2.x * py) + c2.y;
    double z  = (c3.x * px + c3.y * py) + c4.x;
    double w2 = (c4.y - w0) - w1;
    bool ins = (w0 >= 0.0) & (w1 >= 0.0) & (w2 >= 0.0) &
               (z >= -1.0) & (z <= 1.0) & (z < bestz);
    bestz = ins ? z : bestz;
    besti = ins ? (tbase + t) : besti;
  }
  if (besti >= 0) {
    unsigned long long zq = (unsigned long long)((bestz + 1.0) * 4503599627370496.0);
    atomicMin(&keys[y * 128 + x], (zq << 10) | (unsigned long long)besti);
  }
}

__global__ __launch_bounds__(256) void color_kernel(
    const unsigned long long* __restrict__ keys,
    const double* __restrict__ vdata, const double* __restrict__ tridata,
    const int* __restrict__ fidx, const float* __restrict__ vc,
    const float* __restrict__ bg, float* __restrict__ out)
{
  const int p = blockIdx.x * 256 + threadIdx.x;
  if (p >= 16384) return;
  const int x = p & 127, y = p >> 7;
  unsigned long long key = keys[p];
  float cr, cg, cb;
  if (key == ~0ull) {
    cr = bg[0]; cg = bg[1]; cb = bg[2];
  } else {
    unsigned int t = (unsigned int)(key & 1023ull);
    const double* td = tridata + t * TRI_STRIDE;
    double px = (double)x + 0.5, py = (double)y + 0.5;
    double w0 = td[6] * (py - td[1]) - td[7] * (px - td[0]);
    double w1 = td[8] * (py - td[3]) - td[9] * (px - td[2]);
    double w2 = td[10] * (py - td[5]) - td[11] * (px - td[4]);
    double inv = td[15];
    double b0 = w0 * inv, b1 = w1 * inv, b2 = w2 * inv;
    int i0 = fidx[t * 3 + 0], i1 = fidx[t * 3 + 1], i2 = fidx[t * 3 + 2];
    double t0 = b0 * vdata[3 * NV + i0];
    double t1 = b1 * vdata[3 * NV + i1];
    double t2 = b2 * vdata[3 * NV + i2];
    double den = (t0 + t1) + t2;
    if (!(fabs(den) > 1e-8)) den = 1.0;
    cr = (float)((((t0 * (double)vc[i0 * 3 + 0] + t1 * (double)vc[i1 * 3 + 0]) +
                   t2 * (double)vc[i2 * 3 + 0])) / den);
    cg = (float)((((t0 * (double)vc[i0 * 3 + 1] + t1 * (double)vc[i1 * 3 + 1]) +
                   t2 * (double)vc[i2 * 3 + 1])) / den);
    cb = (float)((((t0 * (double)vc[i0 * 3 + 2] + t1 * (double)vc[i1 * 3 + 2]) +
                   t2 * (double)vc[i2 * 3 + 2])) / den);
  }
  out[p * 3 + 0] = cr;
  out[p * 3 + 1] = cg;
  out[p * 3 + 2] = cb;
}

extern "C" void kernel_launch(void* const* d_in, const int* in_sizes, int n_in,
                              void* d_out, int out_size, void* d_ws, size_t ws_size,
                              hipStream_t stream) {
  const float* v = (const float*)d_in[0];
  const float* vc = (const float*)d_in[1];
  const int* fidx = (const int*)d_in[2];
  const float* bg = (const float*)d_in[3];
  const float* camf = (const float*)d_in[4];
  const float* camc = (const float*)d_in[5];
  const float* camt = (const float*)d_in[6];
  const float* camrt = (const float*)d_in[7];
  float* out = (float*)d_out;

  char* ws = (char*)d_ws;
  unsigned long long* keys = (unsigned long long*)ws;   // @0
  double* vdata = (double*)(ws + 131072);
  double* tridata = (double*)(ws + 147456);

  // keys := ~0 (sentinel) — graph-capturable memset node, replaces the
  // serial single-block init loop.
  hipMemsetAsync(keys, 0xFF, 16384 * sizeof(unsigned long long), stream);
  render_kernel<<<dim3(64, NGROUP), 256, 0, stream>>>(
      v, fidx, camf, camc, camt, camrt, vdata, tridata, keys);
  color_kernel<<<64, 256, 0, stream>>>(keys, vdata, tridata, fidx, vc, bg, out);
}